// Round 9
// baseline (152.195 us; speedup 1.0000x reference)
//
#include <hip/hip_runtime.h>
#include <math.h>

// StickBreakingVAE forward, bf16-MFMA, 8-wave blocks, XCD swizzle.
// GEMM1 (AF32): fused f32->bf16 A-staging with 2-deep A-reg prefetch +
// B LDS double-buffer + exact counted vmcnt (T3/T4). Other GEMMs: proven
// r8 single-buffered gll structure. B=32768, D=784, H=500, K=50.

typedef __bf16 bf16x8 __attribute__((ext_vector_type(8)));
typedef float f32x4 __attribute__((ext_vector_type(4)));

#define BATCH 32768
#define BM 128
#define BN 128
#define BK 64
#define NTHR 512

__device__ __forceinline__ unsigned short bf16_bits(float f) {
    __bf16 b = (__bf16)f;
    return __builtin_bit_cast(unsigned short, b);
}

__device__ __forceinline__ void gll16(const unsigned short* src, unsigned short* ldsdst) {
    __builtin_amdgcn_global_load_lds(
        (const __attribute__((address_space(1))) unsigned int*)src,
        (__attribute__((address_space(3))) unsigned int*)ldsdst,
        16, 0, 0);
}

// MODE 0: relu -> bf16 C [ldc]; MODE 1: softplus -> alpha/beta f32 compact;
// MODE 2: sigmoid -> f32 C [B,Nreal] masked.
// AF32: A is f32 [M][lda]; 2-deep reg prefetch + B-dbuf pipeline.
template<int MODE, bool AF32>
__global__ __launch_bounds__(NTHR, 4) void mfma_gemm(
    const void* __restrict__ Av,
    const unsigned short* __restrict__ Bt,  // [Npad][Kpad] bf16 (zero-padded)
    const float* __restrict__ bias,         // [Npad]
    void* __restrict__ Cv,
    int Kpad, int Kreal, int lda, int ldc, int Nreal, int nbx)
{
    constexpr int NBSB = AF32 ? 2 : 1;
    __shared__ unsigned short As[BM * BK];          // linear row*64 + swz-granule*8
    __shared__ unsigned short Bs[NBSB * BN * BK];

    // ---- chunked bijective XCD swizzle (T1, m204) ----
    const int nwg = gridDim.x;
    const int orig = blockIdx.x;
    const int q = nwg >> 3, r8 = nwg & 7;
    const int xcd = orig & 7;
    const int chunkbase = (xcd < r8) ? xcd * (q + 1) : r8 * (q + 1) + (xcd - r8) * q;
    const int wgid = chunkbase + (orig >> 3);
    const int bn = wgid % nbx;               // n fastest -> A-panel L2 reuse
    const size_t block_m = (size_t)(wgid / nbx) * BM;
    const int block_n = bn * BN;

    const int tid = threadIdx.x;
    const int l = tid & 63;
    const int wid = tid >> 6;                // 0..7
    const int wr = wid >> 2, wc = wid & 3;   // wave tile: 64 rows x 32 cols

    const int lr = l & 15;
    const int kh = l >> 4;

    f32x4 acc[4][2] = {};

    auto issueB = [&](int k0, int buf) {
        unsigned short* dst = Bs + buf * (BN * BK);
        #pragma unroll
        for (int i = 0; i < 2; ++i) {
            int chunk = wid * 2 + i;
            int gid = chunk * 64 + l;
            int r = gid >> 3;
            int kgs = (gid & 7) ^ (r & 7);
            gll16(Bt + (size_t)(block_n + r) * Kpad + k0 + kgs * 8, dst + chunk * 512);
        }
    };

    auto compute = [&](int buf) {
        const unsigned short* bsrc = Bs + buf * (BN * BK);
        #pragma unroll
        for (int s = 0; s < 2; ++s) {
            bf16x8 af[4], bf[2];
            #pragma unroll
            for (int mi = 0; mi < 4; ++mi) {
                int row = wr * 64 + mi * 16 + lr;
                int g = (s * 4 + kh) ^ (row & 7);
                af[mi] = *(const bf16x8*)(As + row * 64 + g * 8);
            }
            #pragma unroll
            for (int ni = 0; ni < 2; ++ni) {
                int row = wc * 32 + ni * 16 + lr;
                int g = (s * 4 + kh) ^ (row & 7);
                bf[ni] = *(const bf16x8*)(bsrc + row * 64 + g * 8);
            }
            #pragma unroll
            for (int mi = 0; mi < 4; ++mi)
                #pragma unroll
                for (int ni = 0; ni < 2; ++ni)
                    acc[mi][ni] = __builtin_amdgcn_mfma_f32_16x16x32_bf16(
                        af[mi], bf[ni], acc[mi][ni], 0, 0, 0);
        }
    };

    const int nt = Kpad / BK;

    if constexpr (AF32) {
        const float* Af = (const float*)Av;
        const int clampk = Kreal - 8;

        auto issueA = [&](int k0, float4 (&dst)[4]) {
            #pragma unroll
            for (int i = 0; i < 2; ++i) {
                int gid = i * NTHR + tid;
                int r = gid >> 3, kg = gid & 7;
                int gk = k0 + kg * 8;
                int gkc = (gk <= clampk) ? gk : clampk;   // in-bounds, count-exact
                const float4* p = (const float4*)(Af + (block_m + r) * (size_t)lda + gkc);
                dst[2 * i]     = p[0];
                dst[2 * i + 1] = p[1];
            }
        };
        auto writeA = [&](int t, const float4 (&src)[4]) {
            #pragma unroll
            for (int i = 0; i < 2; ++i) {
                int gid = i * NTHR + tid;
                int r = gid >> 3, kg = gid & 7;
                int gk = t * BK + kg * 8;
                union { __bf16 b[8]; uint4 u4; } pk;
                float4 f0 = src[2 * i], f1 = src[2 * i + 1];
                if (gk < Kreal) {
                    pk.b[0] = (__bf16)f0.x; pk.b[1] = (__bf16)f0.y;
                    pk.b[2] = (__bf16)f0.z; pk.b[3] = (__bf16)f0.w;
                    pk.b[4] = (__bf16)f1.x; pk.b[5] = (__bf16)f1.y;
                    pk.b[6] = (__bf16)f1.z; pk.b[7] = (__bf16)f1.w;
                } else {
                    pk.u4 = make_uint4(0, 0, 0, 0);
                }
                *(uint4*)(As + r * 64 + ((kg ^ (r & 7)) * 8)) = pk.u4;
            }
        };

        float4 aA[4], aB[4];
        // prologue: queue = [B0(2), A0(4), A1(4)]  (order pinned)
        issueB(0, 0);
        __builtin_amdgcn_sched_barrier(0);
        issueA(0, aA);
        issueA(BK, aB);
        __builtin_amdgcn_sched_barrier(0);

        auto step = [&](int t, float4 (&cur)[4]) {
            const int buf = t & 1;
            if (t + 1 < nt) issueB((t + 1) * BK, buf ^ 1);
            __builtin_amdgcn_sched_barrier(0);
            writeA(t, cur);                         // implicit wait drains A(t) (+B(t-?) older)
            if (t + 2 < nt) issueA((t + 2) * BK, cur);
            __builtin_amdgcn_sched_barrier(0);
            // drain B(t); keep {A(t+1),B(t+1),A(t+2)} in flight (counts derived, order pinned)
            if (t + 2 < nt) {
                asm volatile("s_waitcnt vmcnt(10) lgkmcnt(0)" ::: "memory");
            } else if (t + 1 < nt) {
                asm volatile("s_waitcnt vmcnt(6) lgkmcnt(0)" ::: "memory");
            } else {
                asm volatile("s_waitcnt vmcnt(0) lgkmcnt(0)" ::: "memory");
            }
            __builtin_amdgcn_sched_barrier(0);
            __builtin_amdgcn_s_barrier();
            compute(buf);
            __builtin_amdgcn_s_barrier();
        };

        for (int t = 0; t + 1 < nt; t += 2) {      // parity-static regset rotation
            step(t, aA);
            step(t + 1, aB);
        }
        if (nt & 1) step(nt - 1, aA);
    } else {
        // ---- plain single-buffered gll loop (proven r8 structure) ----
        const unsigned short* Ab = (const unsigned short*)Av;
        for (int k0 = 0; k0 < Kpad; k0 += BK) {
            issueB(k0, 0);
            #pragma unroll
            for (int i = 0; i < 2; ++i) {
                int chunk = wid * 2 + i;
                int gid = chunk * 64 + l;
                int r = gid >> 3;
                int kgs = (gid & 7) ^ (r & 7);
                gll16(Ab + (block_m + r) * (size_t)lda + k0 + kgs * 8, As + chunk * 512);
            }
            __syncthreads();
            compute(0);
            __syncthreads();
        }
    }

    // epilogue: C/D layout col=lane&15, row=(lane>>4)*4+j
    const int rg = (l >> 4) * 4;
    #pragma unroll
    for (int mi = 0; mi < 4; ++mi) {
        #pragma unroll
        for (int ni = 0; ni < 2; ++ni) {
            int gn = block_n + wc * 32 + ni * 16 + lr;
            float bs = bias[gn];
            #pragma unroll
            for (int j = 0; j < 4; ++j) {
                long gm = block_m + wr * 64 + mi * 16 + rg + j;
                float z = acc[mi][ni][j] + bs;
                if (MODE == 0) {
                    z = fmaxf(z, 0.f);
                    ((unsigned short*)Cv)[gm * ldc + gn] = bf16_bits(z);
                } else if (MODE == 1) {
                    z = (z > 0.f) ? z + __logf(1.f + __expf(-z))
                                  : __logf(1.f + __expf(z));
                    float* out = (float*)Cv;
                    if (gn < 50)       out[gm * 50 + gn] = z;
                    else if (gn < 100) out[(size_t)BATCH * 50 + gm * 50 + (gn - 50)] = z;
                } else {
                    if (gn < Nreal) {
                        z = __fdividef(1.f, 1.f + __expf(-z));   // single-sided sigmoid
                        ((float*)Cv)[gm * Nreal + gn] = z;
                    }
                }
            }
        }
    }
}

// weight [Kr][Nr] f32 -> [Npad][Kpad] bf16 transposed, bias padded
__global__ __launch_bounds__(256) void prep_bt(
    const float* __restrict__ W, const float* __restrict__ bias,
    unsigned short* __restrict__ Bt, float* __restrict__ bpad,
    int Kr, int Nr, int Kpad, int Npad)
{
    int idx = blockIdx.x * 256 + threadIdx.x;
    if (idx >= Npad * Kpad) return;
    int n = idx / Kpad, k = idx - n * Kpad;
    float v = (n < Nr && k < Kr) ? W[(size_t)k * Nr + n] : 0.f;
    Bt[idx] = bf16_bits(v);
    if (k == 0) bpad[n] = (n < Nr) ? bias[n] : 0.f;
}

// [w_alpha | w_beta] -> [128][512] bf16 transposed
__global__ __launch_bounds__(256) void prep_wab(
    const float* __restrict__ Wa, const float* __restrict__ Wb,
    const float* __restrict__ ba, const float* __restrict__ bb,
    unsigned short* __restrict__ Bt, float* __restrict__ bpad)
{
    int idx = blockIdx.x * 256 + threadIdx.x;
    if (idx >= 128 * 512) return;
    int n = idx >> 9, k = idx & 511;
    float v = 0.f;
    if (k < 500) {
        if (n < 50)       v = Wa[(size_t)k * 50 + n];
        else if (n < 100) v = Wb[(size_t)k * 50 + (n - 50)];
    }
    Bt[idx] = bf16_bits(v);
    if (k == 0) bpad[n] = (n < 50) ? ba[n] : ((n < 100) ? bb[n - 50] : 0.f);
}

// Kumaraswamy sample + stick-breaking: one wave per row, shuffle prefix-product.
__global__ __launch_bounds__(256) void sample_pi(
    const float* __restrict__ u, const float* __restrict__ alpha,
    const float* __restrict__ beta, unsigned short* __restrict__ pib)
{
    int row = (blockIdx.x * 256 + threadIdx.x) >> 6;
    int lane = threadIdx.x & 63;
    size_t base = (size_t)row * 50;

    float v = 0.f, w = 1.f;
    if (lane < 50) {
        float a = alpha[base + lane];
        float b = beta[base + lane];
        float uu = u[base + lane];
        float t = exp2f(__fdividef(log2f(uu), b));          // u^(1/beta)
        v = exp2f(__fdividef(log2f(1.f - t), a));           // (1-t)^(1/alpha)
        w = 1.f - v;
    }
    float p = w;
    #pragma unroll
    for (int off = 1; off < 64; off <<= 1) {
        float t = __shfl_up(p, off, 64);
        if (lane >= off) p *= t;
    }
    float ex = __shfl_up(p, 1, 64);
    if (lane == 0) ex = 1.f;
    float pi = v * ex;
    pib[(size_t)row * 64 + lane] = (lane < 50) ? bf16_bits(pi) : (unsigned short)0;
}

extern "C" void kernel_launch(void* const* d_in, const int* in_sizes, int n_in,
                              void* d_out, int out_size, void* d_ws, size_t ws_size,
                              hipStream_t stream) {
    const float* x       = (const float*)d_in[0];
    const float* u       = (const float*)d_in[1];
    const float* enc_w1  = (const float*)d_in[2];
    const float* enc_b1  = (const float*)d_in[3];
    const float* w_alpha = (const float*)d_in[4];
    const float* b_alpha = (const float*)d_in[5];
    const float* w_beta  = (const float*)d_in[6];
    const float* b_beta  = (const float*)d_in[7];
    const float* dec_w1  = (const float*)d_in[8];
    const float* dec_b1  = (const float*)d_in[9];
    const float* dec_w2  = (const float*)d_in[10];
    const float* dec_b2  = (const float*)d_in[11];

    const int D = 784;

    float* out   = (float*)d_out;
    float* recon = out;                              // [B,784] f32
    float* alpha = out + (size_t)BATCH * D;          // [B,50]; beta at +B*50

    // workspace layout
    char* ws = (char*)d_ws;
    unsigned short* w1b  = (unsigned short*)(ws);             // 512*832*2
    unsigned short* wab  = (unsigned short*)(ws + 851968);    // 128*512*2
    unsigned short* dw1b = (unsigned short*)(ws + 983040);    // 512*64*2
    unsigned short* dw2b = (unsigned short*)(ws + 1048576);   // 896*512*2
    float* bias1  = (float*)(ws + 1966080);
    float* biasab = (float*)(ws + 1968128);
    float* biasd1 = (float*)(ws + 1970688);
    float* biasd2 = (float*)(ws + 1972736);
    unsigned short* h    = (unsigned short*)(ws + 2097152);   // [B][512] bf16
    unsigned short* pib  = (unsigned short*)(ws + 35651584);  // [B][64]  bf16
    unsigned short* hdb  = h;                                  // reuse h
    // peak ws = 39.85 MB

    // ---- prep weights ----
    prep_bt<<<dim3(512 * 832 / 256), 256, 0, stream>>>(
        enc_w1, enc_b1, w1b, bias1, 784, 500, 832, 512);
    prep_wab<<<dim3(256), 256, 0, stream>>>(w_alpha, w_beta, b_alpha, b_beta, wab, biasab);
    prep_bt<<<dim3(512 * 64 / 256), 256, 0, stream>>>(
        dec_w1, dec_b1, dw1b, biasd1, 50, 500, 64, 512);
    prep_bt<<<dim3(896 * 512 / 256), 256, 0, stream>>>(
        dec_w2, dec_b2, dw2b, biasd2, 500, 784, 512, 896);

    // ---- GEMM1: h = relu(x @ enc_w1 + b1), deep-pipelined f32 A-staging ----
    mfma_gemm<0, true><<<dim3((512 / BN) * (BATCH / BM)), NTHR, 0, stream>>>(
        x, w1b, bias1, h, 832, 784, 784, 512, 500, 512 / BN);

    // ---- GEMM2/3: [alpha|beta] = softplus(h @ wab + b) ----
    mfma_gemm<1, false><<<dim3(BATCH / BM), NTHR, 0, stream>>>(
        h, wab, biasab, alpha, 512, 512, 512, 0, 100, 1);

    // ---- sample: one wave per row ----
    sample_pi<<<dim3(BATCH * 64 / 256), 256, 0, stream>>>(
        u, alpha, alpha + (size_t)BATCH * 50, pib);

    // ---- GEMM4: hd = relu(pib @ dec_w1 + b) ----
    mfma_gemm<0, false><<<dim3((512 / BN) * (BATCH / BM)), NTHR, 0, stream>>>(
        pib, dw1b, biasd1, hdb, 64, 64, 64, 512, 500, 512 / BN);

    // ---- GEMM5: recon = sigmoid(hd @ dec_w2 + b) ----
    mfma_gemm<2, false><<<dim3((896 / BN) * (BATCH / BM)), NTHR, 0, stream>>>(
        hdb, dw2b, biasd2, recon, 512, 512, 512, 784, 784, 896 / BN);
}